// Round 5
// baseline (31316.904 us; speedup 1.0000x reference)
//
#include <hip/hip_runtime.h>
#include <stdint.h>

// ---------------------------------------------------------------------------
// RNN-FiLM on MI355X.
// Shapes: B=4, C=2, E=512, H=1024, T=1024, F=513.
// Phases:
//   1. k_gx0: gx0 = emb @ w_ih0^T + b_ih0          (constant over time!)
//   2. k_recur: cooperative persistent kernel, both GRU layers pipelined with
//      one grid barrier per step (1025 steps). Weights in VGPRs, h-vectors
//      staged via LDS, DPP wave reductions. Bounded-spin barrier (no hangs).
//   3. k_film_apply: FiLM GEMM fused with the elementwise apply —
//      scale/shift tile lives in registers, never hits HBM.
// Workspace (16.2 MB): [cnt 8K | yring 64K | h1ring 64K | gx0 48K | h2 16M]
// ---------------------------------------------------------------------------

#define HH 1024
#define BB 4
#define TT 1024
#define EE 512
#define FF 513
#define NWG 256
#define NL0 85            // CUs owning layer-0 units
#define NL1 171           // CUs owning layer-1 units (NL0+NL1 == NWG)
#define NSTEP (TT + 1)    // pipeline depth 1 extra step
#define RMAX 5            // max weight rows per wave
#define WS_NEED 16965632  // bytes of d_ws we require

__device__ __forceinline__ float sigmoidf_(float x) { return 1.0f / (1.0f + expf(-x)); }

// Full wave64 sum via DPP (VALU pipe, keeps LDS pipe free). Result valid in lane 63.
__device__ __forceinline__ float wred_sum(float v) {
  int x = __float_as_int(v);
#define DPPADD(ctrl)                                                          \
  {                                                                           \
    int t_ = __builtin_amdgcn_update_dpp(0, x, (ctrl), 0xF, 0xF, true);       \
    x = __float_as_int(__int_as_float(x) + __int_as_float(t_));               \
  }
  DPPADD(0x111); // row_shr:1
  DPPADD(0x112); // row_shr:2
  DPPADD(0x114); // row_shr:4
  DPPADD(0x118); // row_shr:8   -> lane15 of each row16 holds row sum
  DPPADD(0x142); // row_bcast:15
  DPPADD(0x143); // row_bcast:31 -> lane 63 holds full sum
#undef DPPADD
  return __int_as_float(x);
}

// ------------------------- kernel 1: gx0 -----------------------------------
__global__ void k_gx0(const float* __restrict__ emb,
                      const float* __restrict__ w_ih0,
                      const float* __restrict__ b_ih0,
                      float* __restrict__ gx0) {
  int wave = threadIdx.x >> 6, lane = threadIdx.x & 63;
  int o = blockIdx.x * 4 + wave;  // 0..12287 = b*3072+g
  int b = o / 3072, g = o % 3072;
  const float* wr = w_ih0 + (size_t)g * EE + lane * 8;
  const float* er = emb + (size_t)b * EE + lane * 8;
  float4 w0 = *(const float4*)wr, w1 = *(const float4*)(wr + 4);
  float4 e0 = *(const float4*)er, e1 = *(const float4*)(er + 4);
  float s = w0.x * e0.x + w0.y * e0.y + w0.z * e0.z + w0.w * e0.w +
            w1.x * e1.x + w1.y * e1.y + w1.z * e1.z + w1.w * e1.w;
#pragma unroll
  for (int off = 32; off >= 1; off >>= 1) s += __shfl_xor(s, off);
  if (lane == 0) gx0[(size_t)b * 3072 + g] = s + b_ih0[g];
}

// ------------------------- kernel 2: recurrence ----------------------------
// Role 0 (wg < NL0): owns ~12 layer-0 units; step i computes y[i] from y[i-1].
// Role 1: owns ~6 layer-1 units; step i computes h1[i-1] from y[i-1], h1[i-2]
//   (gx1 and gh1 matvecs fused: waves 0-3 dot y, waves 4-7 dot h1).
// Rows per wave <= 5; lane k-slice: k = j*256 + lane*4 + c (j=0..3, c=0..3)
// -> all global/LDS accesses are consecutive-lane float4 (conflict-free).
__launch_bounds__(512, 2)
__global__ void k_recur(const float* __restrict__ w_hh0,
                        const float* __restrict__ b_hh0,
                        const float* __restrict__ w_ih1,
                        const float* __restrict__ w_hh1,
                        const float* __restrict__ b_ih1,
                        const float* __restrict__ b_hh1,
                        const float* __restrict__ gx0,
                        float* __restrict__ yring,
                        float* __restrict__ h1ring,
                        float* __restrict__ h2,
                        unsigned int* __restrict__ cnt) {
  const int tid = threadIdx.x;
  const int wave = tid >> 6, lane = tid & 63;
  const int wg = blockIdx.x;

  __shared__ float vlds[2][BB][HH];  // [0]=y_prev, [1]=h1_prev (role1 only)
  __shared__ float sums[40][BB];     // role0: rows 0..38 ; role1: gx m, gh 20+m

  int role, u0, nu;
  if (wg < NL0) {
    role = 0;
    const int q = HH / NL0, r = HH % NL0;  // 12, 4
    u0 = wg * q + (wg < r ? wg : r);
    nu = q + (wg < r ? 1 : 0);
  } else {
    role = 1;
    const int k = wg - NL0;
    const int q = HH / NL1, r = HH % NL1;  // 5, 169
    u0 = k * q + (k < r ? k : r);
    nu = q + (k < r ? 1 : 0);
  }
  const int L = 3 * nu;  // rows in this wave's list type
  int lbase, lstride, type;
  if (role == 0) { lbase = wave; lstride = 8; type = 0; }
  else           { lbase = wave & 3; lstride = 4; type = wave >> 2; }
  const float* Wmat = (role == 0) ? w_hh0 : (type == 0 ? w_ih1 : w_hh1);

  // -------- one-time weight preload into VGPRs (static indices only) -------
  float wreg[RMAX][16];
  int nr = 0;
#pragma unroll
  for (int jr = 0; jr < RMAX; ++jr) {
    int m = lbase + lstride * jr;
    if (m < L) {
      int u = m / 3, g = m % 3;
      const float* wp = Wmat + (size_t)(g * HH + u0 + u) * HH;
#pragma unroll
      for (int j = 0; j < 4; ++j) {
        float4 v = *(const float4*)(wp + j * 256 + lane * 4);
        wreg[jr][j * 4 + 0] = v.x; wreg[jr][j * 4 + 1] = v.y;
        wreg[jr][j * 4 + 2] = v.z; wreg[jr][j * 4 + 3] = v.w;
      }
      nr = jr + 1;
    }
  }

  // -------- gate-thread constants (gate threads all live in wave 0) --------
  const int gu = tid >> 2, gb = tid & 3;
  const bool gate = (tid < nu * 4);
  const int gj = u0 + gu;
  float c0 = 0.f, c1 = 0.f, c2 = 0.f, c3 = 0.f, c4 = 0.f, c5 = 0.f;
  if (gate) {
    if (role == 0) {  // gx0 (already includes b_ih0) + b_hh0
      c0 = gx0[(size_t)gb * 3072 + gj];
      c1 = gx0[(size_t)gb * 3072 + HH + gj];
      c2 = gx0[(size_t)gb * 3072 + 2 * HH + gj];
      c3 = b_hh0[gj]; c4 = b_hh0[HH + gj]; c5 = b_hh0[2 * HH + gj];
    } else {
      c0 = b_ih1[gj]; c1 = b_ih1[HH + gj]; c2 = b_ih1[2 * HH + gj];
      c3 = b_hh1[gj]; c4 = b_hh1[HH + gj]; c5 = b_hh1[2 * HH + gj];
    }
  }

  for (int i = 0; i < NSTEP; ++i) {
    const bool active = (role == 0) ? (i < TT) : (i >= 1);
    if (active) {
      // ---- stage vectors global -> LDS (16KB each, coalesced) ----
      {
        const float4* src = (const float4*)(yring + (size_t)((i + 3) & 3) * BB * HH);
        float4* dst = (float4*)&vlds[0][0][0];
        dst[tid * 2] = src[tid * 2];
        dst[tid * 2 + 1] = src[tid * 2 + 1];
      }
      if (role == 1) {
        const float4* src = (const float4*)(h1ring + (size_t)((i + 2) & 3) * BB * HH);
        float4* dst = (float4*)&vlds[1][0][0];
        dst[tid * 2] = src[tid * 2];
        dst[tid * 2 + 1] = src[tid * 2 + 1];
      }
      __syncthreads();

      // ---- load this lane's h fragments (16 x ds_read_b128, no conflicts) --
      float vreg[BB][16];
      const float* vb = &vlds[type][0][0];
#pragma unroll
      for (int b = 0; b < BB; ++b)
#pragma unroll
        for (int j = 0; j < 4; ++j) {
          float4 v = *(const float4*)(vb + b * HH + j * 256 + lane * 4);
          vreg[b][j * 4 + 0] = v.x; vreg[b][j * 4 + 1] = v.y;
          vreg[b][j * 4 + 2] = v.z; vreg[b][j * 4 + 3] = v.w;
        }

      // ---- matvec partials ----
      float acc[RMAX][BB];
#pragma unroll
      for (int jr = 0; jr < RMAX; ++jr)
#pragma unroll
        for (int b = 0; b < BB; ++b) acc[jr][b] = 0.f;
#pragma unroll
      for (int jr = 0; jr < RMAX; ++jr)
        if (jr < nr)
#pragma unroll
          for (int kk = 0; kk < 16; ++kk)
#pragma unroll
            for (int b = 0; b < BB; ++b)
              acc[jr][b] = fmaf(wreg[jr][kk], vreg[b][kk], acc[jr][b]);

      // ---- wave reductions (DPP, result in lane 63) ----
#pragma unroll
      for (int jr = 0; jr < RMAX; ++jr)
        if (jr < nr) {
          int m = lbase + lstride * jr;
#pragma unroll
          for (int b = 0; b < BB; ++b) {
            float s = wred_sum(acc[jr][b]);
            if (lane == 63) sums[(type ? 20 : 0) + m][b] = s;
          }
        }
      __syncthreads();

      // ---- gate math (<=52 threads, all in wave 0) ----
      if (gate) {
        if (role == 0) {
          float ghr = sums[3 * gu + 0][gb] + c3;
          float ghz = sums[3 * gu + 1][gb] + c4;
          float ghn = sums[3 * gu + 2][gb] + c5;
          float r_ = sigmoidf_(c0 + ghr);
          float z_ = sigmoidf_(c1 + ghz);
          float n_ = tanhf(c2 + r_ * ghn);
          float hp = vlds[0][gb][gj];
          float hn = (1.f - z_) * n_ + z_ * hp;
          yring[(size_t)(i & 3) * BB * HH + (size_t)gb * HH + gj] = hn;
        } else {
          float gxr = sums[3 * gu + 0][gb] + c0;
          float gxz = sums[3 * gu + 1][gb] + c1;
          float gxn = sums[3 * gu + 2][gb] + c2;
          float ghr = sums[20 + 3 * gu + 0][gb] + c3;
          float ghz = sums[20 + 3 * gu + 1][gb] + c4;
          float ghn = sums[20 + 3 * gu + 2][gb] + c5;
          float r_ = sigmoidf_(gxr + ghr);
          float z_ = sigmoidf_(gxz + ghz);
          float n_ = tanhf(gxn + r_ * ghn);
          float hp = vlds[1][gb][gj];
          float hn = (1.f - z_) * n_ + z_ * hp;
          int t = i - 1;
          h1ring[(size_t)((i + 3) & 3) * BB * HH + (size_t)gb * HH + gj] = hn;
          h2[((size_t)gb * TT + t) * HH + gj] = hn;
        }
      }
    }
    // ---- grid barrier (bounded spin: a broken barrier -> wrong answer in
    // ~3.5ms/step, never a hung container). All global writes above came
    // from wave 0, so tid 0's release fetch_add publishes them. ----
    __syncthreads();
    if (tid == 0) {
      __hip_atomic_fetch_add(&cnt[i], 1u, __ATOMIC_RELEASE, __HIP_MEMORY_SCOPE_AGENT);
      int tries = 0;
      while (__hip_atomic_load(&cnt[i], __ATOMIC_RELAXED, __HIP_MEMORY_SCOPE_AGENT) < NWG &&
             tries < 65536) {
        __builtin_amdgcn_s_sleep(2);
        ++tries;
      }
    }
    __syncthreads();
    __builtin_amdgcn_fence(__ATOMIC_ACQUIRE, "agent");
  }
}

// ------------------- kernel 3: FiLM GEMM + apply (fused) -------------------
// Per block: compute the 64(t) x 64(f) scale/shift tile for batch b1 in
// registers, then apply to all 8 (b2,c) x-tiles:
//   out[b1][b2][c][f][t] = x[b2][c][f][t] * S[b1][f][t] + Sh[b1][f][t]
__global__ void k_film_apply(const float* __restrict__ h2,
                             const float* __restrict__ w_scale,
                             const float* __restrict__ b_scale,
                             const float* __restrict__ w_shift,
                             const float* __restrict__ b_shift,
                             const float* __restrict__ x,
                             float* __restrict__ out) {
  __shared__ float As[64][36];
  __shared__ float Ws[2][64][36];
  const int tid = threadIdx.x;
  const int t0 = blockIdx.x * 64, f0 = blockIdx.y * 64, b1 = blockIdx.z;
  const int tx = tid & 15, ty = tid >> 4;
  float accS[4][4], accH[4][4];  // [i over t][j over f]
#pragma unroll
  for (int i = 0; i < 4; ++i)
#pragma unroll
    for (int j = 0; j < 4; ++j) { accS[i][j] = 0.f; accH[i][j] = 0.f; }

  const int lrow = tid >> 2, lj = tid & 3;
  for (int k0 = 0; k0 < HH; k0 += 32) {
    {
      const float* src = h2 + ((size_t)b1 * TT + (t0 + lrow)) * HH + k0;
      *(float4*)&As[lrow][lj * 4] = *(const float4*)(src + lj * 4);
      *(float4*)&As[lrow][(lj + 4) * 4] = *(const float4*)(src + (lj + 4) * 4);
    }
    {
      int f = f0 + lrow;
      float4 z4 = make_float4(0.f, 0.f, 0.f, 0.f);
      bool ok = (f < FF);
      const float* ss = w_scale + (size_t)f * HH + k0;
      const float* sh = w_shift + (size_t)f * HH + k0;
      *(float4*)&Ws[0][lrow][lj * 4] = ok ? *(const float4*)(ss + lj * 4) : z4;
      *(float4*)&Ws[0][lrow][(lj + 4) * 4] = ok ? *(const float4*)(ss + (lj + 4) * 4) : z4;
      *(float4*)&Ws[1][lrow][lj * 4] = ok ? *(const float4*)(sh + lj * 4) : z4;
      *(float4*)&Ws[1][lrow][(lj + 4) * 4] = ok ? *(const float4*)(sh + (lj + 4) * 4) : z4;
    }
    __syncthreads();
#pragma unroll
    for (int kk = 0; kk < 32; kk += 4) {
      float4 a4[4], s4[4], h4[4];
#pragma unroll
      for (int i = 0; i < 4; ++i) a4[i] = *(const float4*)&As[tx * 4 + i][kk];
#pragma unroll
      for (int j = 0; j < 4; ++j) {
        s4[j] = *(const float4*)&Ws[0][ty * 4 + j][kk];
        h4[j] = *(const float4*)&Ws[1][ty * 4 + j][kk];
      }
#pragma unroll
      for (int i = 0; i < 4; ++i)
#pragma unroll
        for (int j = 0; j < 4; ++j) {
          accS[i][j] = fmaf(a4[i].x, s4[j].x, accS[i][j]);
          accS[i][j] = fmaf(a4[i].y, s4[j].y, accS[i][j]);
          accS[i][j] = fmaf(a4[i].z, s4[j].z, accS[i][j]);
          accS[i][j] = fmaf(a4[i].w, s4[j].w, accS[i][j]);
          accH[i][j] = fmaf(a4[i].x, h4[j].x, accH[i][j]);
          accH[i][j] = fmaf(a4[i].y, h4[j].y, accH[i][j]);
          accH[i][j] = fmaf(a4[i].z, h4[j].z, accH[i][j]);
          accH[i][j] = fmaf(a4[i].w, h4[j].w, accH[i][j]);
        }
    }
    __syncthreads();
  }

  // ---- apply phase: this thread owns t = t0+tx*4..+3, f = f0+ty*4+j ----
#pragma unroll
  for (int j = 0; j < 4; ++j) {
    const int f = f0 + ty * 4 + j;
    if (f < FF) {
      const float bs = b_scale[f], bh = b_shift[f];
      const float s0 = accS[0][j] + bs, s1 = accS[1][j] + bs,
                  s2 = accS[2][j] + bs, s3 = accS[3][j] + bs;
      const float h0 = accH[0][j] + bh, h1 = accH[1][j] + bh,
                  h2v = accH[2][j] + bh, h3 = accH[3][j] + bh;
#pragma unroll
      for (int bc = 0; bc < 8; ++bc) {
        const int b2 = bc >> 1, c = bc & 1;
        const float4 xv = *(const float4*)(
            x + ((size_t)(b2 * 2 + c) * FF + f) * TT + t0 + tx * 4);
        float4 o;
        o.x = fmaf(xv.x, s0, h0);
        o.y = fmaf(xv.y, s1, h1);
        o.z = fmaf(xv.z, s2, h2v);
        o.w = fmaf(xv.w, s3, h3);
        *(float4*)(out + ((((size_t)b1 * 4 + b2) * 2 + c) * FF + f) * TT +
                   t0 + tx * 4) = o;
      }
    }
  }
}

// ------------------------- host launch -------------------------------------
extern "C" void kernel_launch(void* const* d_in, const int* in_sizes, int n_in,
                              void* d_out, int out_size, void* d_ws, size_t ws_size,
                              hipStream_t stream) {
  const float* x = (const float*)d_in[0];
  const float* emb = (const float*)d_in[1];
  const float* w_ih0 = (const float*)d_in[2];
  const float* w_hh0 = (const float*)d_in[3];
  const float* b_ih0 = (const float*)d_in[4];
  const float* b_hh0 = (const float*)d_in[5];
  const float* w_ih1 = (const float*)d_in[6];
  const float* w_hh1 = (const float*)d_in[7];
  const float* b_ih1 = (const float*)d_in[8];
  const float* b_hh1 = (const float*)d_in[9];
  const float* w_scale = (const float*)d_in[10];
  const float* b_scale = (const float*)d_in[11];
  const float* w_shift = (const float*)d_in[12];
  const float* b_shift = (const float*)d_in[13];
  float* out = (float*)d_out;

  if (ws_size < (size_t)WS_NEED) return;  // clean fail (diagnosable), no OOB

  // workspace layout (16.2 MB)
  char* ws = (char*)d_ws;
  unsigned int* cnt = (unsigned int*)(ws + 0);       //  8 KB  (NSTEP u32, zeroed)
  float* yring = (float*)(ws + 8192);                // 64 KB  (4 slots x [4][1024])
  float* h1ring = (float*)(ws + 73728);              // 64 KB
  float* gx0 = (float*)(ws + 139264);                // 48 KB
  float* h2 = (float*)(ws + 188416);                 // 16 MB  [4][1024][1024]

  // counters + rings must be zero every call (ws is re-poisoned by harness)
  (void)hipMemsetAsync(d_ws, 0, 139264, stream);

  k_gx0<<<dim3(3072), dim3(256), 0, stream>>>(emb, w_ih0, b_ih0, gx0);

  void* args[] = {(void*)&w_hh0, (void*)&b_hh0, (void*)&w_ih1, (void*)&w_hh1,
                  (void*)&b_ih1, (void*)&b_hh1, (void*)&gx0,   (void*)&yring,
                  (void*)&h1ring, (void*)&h2,   (void*)&cnt};
  hipError_t ce = hipLaunchCooperativeKernel((void*)k_recur, dim3(NWG), dim3(512),
                                             args, 0, stream);
  if (ce != hipSuccess) {
    // fallback: plain launch; 256 WGs on 256 CUs co-reside, barrier still works
    k_recur<<<dim3(NWG), dim3(512), 0, stream>>>(w_hh0, b_hh0, w_ih1, w_hh1,
                                                 b_ih1, b_hh1, gx0, yring,
                                                 h1ring, h2, cnt);
  }

  k_film_apply<<<dim3(16, 9, 4), dim3(256), 0, stream>>>(
      h2, w_scale, b_scale, w_shift, b_shift, x, out);
}

// Round 6
// 24862.828 us; speedup vs baseline: 1.2596x; 1.2596x over previous
//
#include <hip/hip_runtime.h>
#include <stdint.h>

// ---------------------------------------------------------------------------
// RNN-FiLM on MI355X.
// Shapes: B=4, C=2, E=512, H=1024, T=1024, F=513.
// Phases:
//   1. k_gx0: gx0 = emb @ w_ih0^T + b_ih0          (constant over time!)
//   2. k_recur: cooperative persistent kernel, both GRU layers pipelined with
//      one grid barrier per step (1025 steps). Weights in VGPRs, h-vectors
//      staged via LDS, DPP wave reductions.
//      R6: flag-array + master-broadcast barrier (NO serialized same-line
//      atomics — R5 counters showed 28us/step lost to 256 fetch_adds on one
//      cacheline; VALUBusy 6.5%, compute only ~2us/step).
//   3. k_film_apply: FiLM GEMM fused with the elementwise apply —
//      scale/shift tile lives in registers, never hits HBM.
// Workspace (16.2 MB): [flags 16K | go 16K | yring 64K | h1ring 64K | gx0 48K | h2 16M]
// ---------------------------------------------------------------------------

#define HH 1024
#define BB 4
#define TT 1024
#define EE 512
#define FF 513
#define NWG 256
#define NL0 85            // CUs owning layer-0 units
#define NL1 171           // CUs owning layer-1 units (NL0+NL1 == NWG)
#define NSTEP (TT + 1)    // pipeline depth 1 extra step
#define RMAX 5            // max weight rows per wave
#define WS_NEED 16990208  // bytes of d_ws we require

__device__ __forceinline__ float sigmoidf_(float x) { return 1.0f / (1.0f + expf(-x)); }

// Full wave64 sum via DPP (VALU pipe, keeps LDS pipe free). Result valid in lane 63.
__device__ __forceinline__ float wred_sum(float v) {
  int x = __float_as_int(v);
#define DPPADD(ctrl)                                                          \
  {                                                                           \
    int t_ = __builtin_amdgcn_update_dpp(0, x, (ctrl), 0xF, 0xF, true);       \
    x = __float_as_int(__int_as_float(x) + __int_as_float(t_));               \
  }
  DPPADD(0x111); // row_shr:1
  DPPADD(0x112); // row_shr:2
  DPPADD(0x114); // row_shr:4
  DPPADD(0x118); // row_shr:8   -> lane15 of each row16 holds row sum
  DPPADD(0x142); // row_bcast:15
  DPPADD(0x143); // row_bcast:31 -> lane 63 holds full sum
#undef DPPADD
  return __int_as_float(x);
}

// ------------------------- kernel 1: gx0 -----------------------------------
__global__ void k_gx0(const float* __restrict__ emb,
                      const float* __restrict__ w_ih0,
                      const float* __restrict__ b_ih0,
                      float* __restrict__ gx0) {
  int wave = threadIdx.x >> 6, lane = threadIdx.x & 63;
  int o = blockIdx.x * 4 + wave;  // 0..12287 = b*3072+g
  int b = o / 3072, g = o % 3072;
  const float* wr = w_ih0 + (size_t)g * EE + lane * 8;
  const float* er = emb + (size_t)b * EE + lane * 8;
  float4 w0 = *(const float4*)wr, w1 = *(const float4*)(wr + 4);
  float4 e0 = *(const float4*)er, e1 = *(const float4*)(er + 4);
  float s = w0.x * e0.x + w0.y * e0.y + w0.z * e0.z + w0.w * e0.w +
            w1.x * e1.x + w1.y * e1.y + w1.z * e1.z + w1.w * e1.w;
#pragma unroll
  for (int off = 32; off >= 1; off >>= 1) s += __shfl_xor(s, off);
  if (lane == 0) gx0[(size_t)b * 3072 + g] = s + b_ih0[g];
}

// ------------------------- kernel 2: recurrence ----------------------------
// Role 0 (wg < NL0): owns ~12 layer-0 units; step i computes y[i] from y[i-1].
// Role 1: owns ~6 layer-1 units; step i computes h1[i-1] from y[i-1], h1[i-2]
//   (gx1 and gh1 matvecs fused: waves 0-3 dot y, waves 4-7 dot h1).
// Rows per wave <= 5; lane k-slice: k = j*256 + lane*4 + c (j=0..3, c=0..3)
// -> all global/LDS accesses are consecutive-lane float4 (conflict-free).
//
// Barrier (R6): WG w release-stores flags[w*16]=i+1 (own cacheline, all 256
// stores parallel). Master (wg 0, wave 0) polls all flags (4 loads/lane x 64
// lanes), acquire-fences, release-stores go=i+1. Consumers poll go with
// wave-coalesced same-address loads. Monotonic values: no reset, no ABA.
// Zero serialized RMWs.
__launch_bounds__(512, 2)
__global__ void k_recur(const float* __restrict__ w_hh0,
                        const float* __restrict__ b_hh0,
                        const float* __restrict__ w_ih1,
                        const float* __restrict__ w_hh1,
                        const float* __restrict__ b_ih1,
                        const float* __restrict__ b_hh1,
                        const float* __restrict__ gx0,
                        float* __restrict__ yring,
                        float* __restrict__ h1ring,
                        float* __restrict__ h2,
                        unsigned int* __restrict__ flags,
                        unsigned int* __restrict__ go) {
  const int tid = threadIdx.x;
  const int wave = tid >> 6, lane = tid & 63;
  const int wg = blockIdx.x;

  __shared__ float vlds[2][BB][HH];  // [0]=y_prev, [1]=h1_prev (role1 only)
  __shared__ float sums[40][BB];     // role0: rows 0..38 ; role1: gx m, gh 20+m

  int role, u0, nu;
  if (wg < NL0) {
    role = 0;
    const int q = HH / NL0, r = HH % NL0;  // 12, 4
    u0 = wg * q + (wg < r ? wg : r);
    nu = q + (wg < r ? 1 : 0);
  } else {
    role = 1;
    const int k = wg - NL0;
    const int q = HH / NL1, r = HH % NL1;  // 5, 169
    u0 = k * q + (k < r ? k : r);
    nu = q + (k < r ? 1 : 0);
  }
  const int L = 3 * nu;  // rows in this wave's list type
  int lbase, lstride, type;
  if (role == 0) { lbase = wave; lstride = 8; type = 0; }
  else           { lbase = wave & 3; lstride = 4; type = wave >> 2; }
  const float* Wmat = (role == 0) ? w_hh0 : (type == 0 ? w_ih1 : w_hh1);

  // -------- one-time weight preload into VGPRs (static indices only) -------
  float wreg[RMAX][16];
  int nr = 0;
#pragma unroll
  for (int jr = 0; jr < RMAX; ++jr) {
    int m = lbase + lstride * jr;
    if (m < L) {
      int u = m / 3, g = m % 3;
      const float* wp = Wmat + (size_t)(g * HH + u0 + u) * HH;
#pragma unroll
      for (int j = 0; j < 4; ++j) {
        float4 v = *(const float4*)(wp + j * 256 + lane * 4);
        wreg[jr][j * 4 + 0] = v.x; wreg[jr][j * 4 + 1] = v.y;
        wreg[jr][j * 4 + 2] = v.z; wreg[jr][j * 4 + 3] = v.w;
      }
      nr = jr + 1;
    }
  }

  // -------- gate-thread constants (gate threads all live in wave 0) --------
  const int gu = tid >> 2, gb = tid & 3;
  const bool gate = (tid < nu * 4);
  const int gj = u0 + gu;
  float c0 = 0.f, c1 = 0.f, c2 = 0.f, c3 = 0.f, c4 = 0.f, c5 = 0.f;
  if (gate) {
    if (role == 0) {  // gx0 (already includes b_ih0) + b_hh0
      c0 = gx0[(size_t)gb * 3072 + gj];
      c1 = gx0[(size_t)gb * 3072 + HH + gj];
      c2 = gx0[(size_t)gb * 3072 + 2 * HH + gj];
      c3 = b_hh0[gj]; c4 = b_hh0[HH + gj]; c5 = b_hh0[2 * HH + gj];
    } else {
      c0 = b_ih1[gj]; c1 = b_ih1[HH + gj]; c2 = b_ih1[2 * HH + gj];
      c3 = b_hh1[gj]; c4 = b_hh1[HH + gj]; c5 = b_hh1[2 * HH + gj];
    }
  }

  for (int i = 0; i < NSTEP; ++i) {
    const bool active = (role == 0) ? (i < TT) : (i >= 1);
    if (active) {
      // ---- stage vectors global -> LDS (16KB each, coalesced) ----
      {
        const float4* src = (const float4*)(yring + (size_t)((i + 3) & 3) * BB * HH);
        float4* dst = (float4*)&vlds[0][0][0];
        dst[tid * 2] = src[tid * 2];
        dst[tid * 2 + 1] = src[tid * 2 + 1];
      }
      if (role == 1) {
        const float4* src = (const float4*)(h1ring + (size_t)((i + 2) & 3) * BB * HH);
        float4* dst = (float4*)&vlds[1][0][0];
        dst[tid * 2] = src[tid * 2];
        dst[tid * 2 + 1] = src[tid * 2 + 1];
      }
      __syncthreads();

      // ---- load this lane's h fragments (16 x ds_read_b128, no conflicts) --
      float vreg[BB][16];
      const float* vb = &vlds[type][0][0];
#pragma unroll
      for (int b = 0; b < BB; ++b)
#pragma unroll
        for (int j = 0; j < 4; ++j) {
          float4 v = *(const float4*)(vb + b * HH + j * 256 + lane * 4);
          vreg[b][j * 4 + 0] = v.x; vreg[b][j * 4 + 1] = v.y;
          vreg[b][j * 4 + 2] = v.z; vreg[b][j * 4 + 3] = v.w;
        }

      // ---- matvec partials ----
      float acc[RMAX][BB];
#pragma unroll
      for (int jr = 0; jr < RMAX; ++jr)
#pragma unroll
        for (int b = 0; b < BB; ++b) acc[jr][b] = 0.f;
#pragma unroll
      for (int jr = 0; jr < RMAX; ++jr)
        if (jr < nr)
#pragma unroll
          for (int kk = 0; kk < 16; ++kk)
#pragma unroll
            for (int b = 0; b < BB; ++b)
              acc[jr][b] = fmaf(wreg[jr][kk], vreg[b][kk], acc[jr][b]);

      // ---- wave reductions (DPP, result in lane 63) ----
#pragma unroll
      for (int jr = 0; jr < RMAX; ++jr)
        if (jr < nr) {
          int m = lbase + lstride * jr;
#pragma unroll
          for (int b = 0; b < BB; ++b) {
            float s = wred_sum(acc[jr][b]);
            if (lane == 63) sums[(type ? 20 : 0) + m][b] = s;
          }
        }
      __syncthreads();

      // ---- gate math (<=52 threads, all in wave 0) ----
      if (gate) {
        if (role == 0) {
          float ghr = sums[3 * gu + 0][gb] + c3;
          float ghz = sums[3 * gu + 1][gb] + c4;
          float ghn = sums[3 * gu + 2][gb] + c5;
          float r_ = sigmoidf_(c0 + ghr);
          float z_ = sigmoidf_(c1 + ghz);
          float n_ = tanhf(c2 + r_ * ghn);
          float hp = vlds[0][gb][gj];
          float hn = (1.f - z_) * n_ + z_ * hp;
          yring[(size_t)(i & 3) * BB * HH + (size_t)gb * HH + gj] = hn;
        } else {
          float gxr = sums[3 * gu + 0][gb] + c0;
          float gxz = sums[3 * gu + 1][gb] + c1;
          float gxn = sums[3 * gu + 2][gb] + c2;
          float ghr = sums[20 + 3 * gu + 0][gb] + c3;
          float ghz = sums[20 + 3 * gu + 1][gb] + c4;
          float ghn = sums[20 + 3 * gu + 2][gb] + c5;
          float r_ = sigmoidf_(gxr + ghr);
          float z_ = sigmoidf_(gxz + ghz);
          float n_ = tanhf(gxn + r_ * ghn);
          float hp = vlds[1][gb][gj];
          float hn = (1.f - z_) * n_ + z_ * hp;
          int t = i - 1;
          h1ring[(size_t)((i + 3) & 3) * BB * HH + (size_t)gb * HH + gj] = hn;
          h2[((size_t)gb * TT + t) * HH + gj] = hn;
        }
      }
    }

    // ---- flag/master-broadcast grid barrier (no serialized RMWs) ----
    // All global data writes above came from wave 0; the release store of
    // this WG's flag (by a wave-0 lane) publishes them.
    __syncthreads();
    const unsigned int want = (unsigned int)(i + 1);
    if (wg == 0) {
      if (wave == 0) {
        if (lane == 0)
          __hip_atomic_store(&flags[0], want, __ATOMIC_RELEASE, __HIP_MEMORY_SCOPE_AGENT);
        // poll all 256 flags: lane covers w = lane, lane+64, lane+128, lane+192
        int tries = 0;
        for (;;) {
          unsigned int f0 = __hip_atomic_load(&flags[(lane + 0) * 16], __ATOMIC_RELAXED, __HIP_MEMORY_SCOPE_AGENT);
          unsigned int f1 = __hip_atomic_load(&flags[(lane + 64) * 16], __ATOMIC_RELAXED, __HIP_MEMORY_SCOPE_AGENT);
          unsigned int f2 = __hip_atomic_load(&flags[(lane + 128) * 16], __ATOMIC_RELAXED, __HIP_MEMORY_SCOPE_AGENT);
          unsigned int f3 = __hip_atomic_load(&flags[(lane + 192) * 16], __ATOMIC_RELAXED, __HIP_MEMORY_SCOPE_AGENT);
          bool ok = (f0 >= want) && (f1 >= want) && (f2 >= want) && (f3 >= want);
          if (__all(ok) || ++tries >= 16384) break;
        }
        __builtin_amdgcn_fence(__ATOMIC_ACQUIRE, "agent");
        if (lane == 0)
          __hip_atomic_store(go, want, __ATOMIC_RELEASE, __HIP_MEMORY_SCOPE_AGENT);
      }
      __syncthreads();
    } else {
      if (tid == 0)
        __hip_atomic_store(&flags[wg * 16], want, __ATOMIC_RELEASE, __HIP_MEMORY_SCOPE_AGENT);
      if (wave == 0) {
        // whole wave polls the same address -> coalesced to 1 request/poll
        int tries = 0;
        while (__hip_atomic_load(go, __ATOMIC_RELAXED, __HIP_MEMORY_SCOPE_AGENT) < want &&
               ++tries < 32768)
          __builtin_amdgcn_s_sleep(1);
      }
      __syncthreads();
    }
    __builtin_amdgcn_fence(__ATOMIC_ACQUIRE, "agent");
  }
}

// ------------------- kernel 3: FiLM GEMM + apply (fused) -------------------
// Per block: compute the 64(t) x 64(f) scale/shift tile for batch b1 in
// registers, then apply to all 8 (b2,c) x-tiles:
//   out[b1][b2][c][f][t] = x[b2][c][f][t] * S[b1][f][t] + Sh[b1][f][t]
__global__ void k_film_apply(const float* __restrict__ h2,
                             const float* __restrict__ w_scale,
                             const float* __restrict__ b_scale,
                             const float* __restrict__ w_shift,
                             const float* __restrict__ b_shift,
                             const float* __restrict__ x,
                             float* __restrict__ out) {
  __shared__ float As[64][36];
  __shared__ float Ws[2][64][36];
  const int tid = threadIdx.x;
  const int t0 = blockIdx.x * 64, f0 = blockIdx.y * 64, b1 = blockIdx.z;
  const int tx = tid & 15, ty = tid >> 4;
  float accS[4][4], accH[4][4];  // [i over t][j over f]
#pragma unroll
  for (int i = 0; i < 4; ++i)
#pragma unroll
    for (int j = 0; j < 4; ++j) { accS[i][j] = 0.f; accH[i][j] = 0.f; }

  const int lrow = tid >> 2, lj = tid & 3;
  for (int k0 = 0; k0 < HH; k0 += 32) {
    {
      const float* src = h2 + ((size_t)b1 * TT + (t0 + lrow)) * HH + k0;
      *(float4*)&As[lrow][lj * 4] = *(const float4*)(src + lj * 4);
      *(float4*)&As[lrow][(lj + 4) * 4] = *(const float4*)(src + (lj + 4) * 4);
    }
    {
      int f = f0 + lrow;
      float4 z4 = make_float4(0.f, 0.f, 0.f, 0.f);
      bool ok = (f < FF);
      const float* ss = w_scale + (size_t)f * HH + k0;
      const float* sh = w_shift + (size_t)f * HH + k0;
      *(float4*)&Ws[0][lrow][lj * 4] = ok ? *(const float4*)(ss + lj * 4) : z4;
      *(float4*)&Ws[0][lrow][(lj + 4) * 4] = ok ? *(const float4*)(ss + (lj + 4) * 4) : z4;
      *(float4*)&Ws[1][lrow][lj * 4] = ok ? *(const float4*)(sh + lj * 4) : z4;
      *(float4*)&Ws[1][lrow][(lj + 4) * 4] = ok ? *(const float4*)(sh + (lj + 4) * 4) : z4;
    }
    __syncthreads();
#pragma unroll
    for (int kk = 0; kk < 32; kk += 4) {
      float4 a4[4], s4[4], h4[4];
#pragma unroll
      for (int i = 0; i < 4; ++i) a4[i] = *(const float4*)&As[tx * 4 + i][kk];
#pragma unroll
      for (int j = 0; j < 4; ++j) {
        s4[j] = *(const float4*)&Ws[0][ty * 4 + j][kk];
        h4[j] = *(const float4*)&Ws[1][ty * 4 + j][kk];
      }
#pragma unroll
      for (int i = 0; i < 4; ++i)
#pragma unroll
        for (int j = 0; j < 4; ++j) {
          accS[i][j] = fmaf(a4[i].x, s4[j].x, accS[i][j]);
          accS[i][j] = fmaf(a4[i].y, s4[j].y, accS[i][j]);
          accS[i][j] = fmaf(a4[i].z, s4[j].z, accS[i][j]);
          accS[i][j] = fmaf(a4[i].w, s4[j].w, accS[i][j]);
          accH[i][j] = fmaf(a4[i].x, h4[j].x, accH[i][j]);
          accH[i][j] = fmaf(a4[i].y, h4[j].y, accH[i][j]);
          accH[i][j] = fmaf(a4[i].z, h4[j].z, accH[i][j]);
          accH[i][j] = fmaf(a4[i].w, h4[j].w, accH[i][j]);
        }
    }
    __syncthreads();
  }

  // ---- apply phase: this thread owns t = t0+tx*4..+3, f = f0+ty*4+j ----
#pragma unroll
  for (int j = 0; j < 4; ++j) {
    const int f = f0 + ty * 4 + j;
    if (f < FF) {
      const float bs = b_scale[f], bh = b_shift[f];
      const float s0 = accS[0][j] + bs, s1 = accS[1][j] + bs,
                  s2 = accS[2][j] + bs, s3 = accS[3][j] + bs;
      const float h0 = accH[0][j] + bh, h1 = accH[1][j] + bh,
                  h2v = accH[2][j] + bh, h3 = accH[3][j] + bh;
#pragma unroll
      for (int bc = 0; bc < 8; ++bc) {
        const int b2 = bc >> 1, c = bc & 1;
        const float4 xv = *(const float4*)(
            x + ((size_t)(b2 * 2 + c) * FF + f) * TT + t0 + tx * 4);
        float4 o;
        o.x = fmaf(xv.x, s0, h0);
        o.y = fmaf(xv.y, s1, h1);
        o.z = fmaf(xv.z, s2, h2v);
        o.w = fmaf(xv.w, s3, h3);
        *(float4*)(out + ((((size_t)b1 * 4 + b2) * 2 + c) * FF + f) * TT +
                   t0 + tx * 4) = o;
      }
    }
  }
}

// ------------------------- host launch -------------------------------------
extern "C" void kernel_launch(void* const* d_in, const int* in_sizes, int n_in,
                              void* d_out, int out_size, void* d_ws, size_t ws_size,
                              hipStream_t stream) {
  const float* x = (const float*)d_in[0];
  const float* emb = (const float*)d_in[1];
  const float* w_ih0 = (const float*)d_in[2];
  const float* w_hh0 = (const float*)d_in[3];
  const float* b_ih0 = (const float*)d_in[4];
  const float* b_hh0 = (const float*)d_in[5];
  const float* w_ih1 = (const float*)d_in[6];
  const float* w_hh1 = (const float*)d_in[7];
  const float* b_ih1 = (const float*)d_in[8];
  const float* b_hh1 = (const float*)d_in[9];
  const float* w_scale = (const float*)d_in[10];
  const float* b_scale = (const float*)d_in[11];
  const float* w_shift = (const float*)d_in[12];
  const float* b_shift = (const float*)d_in[13];
  float* out = (float*)d_out;

  if (ws_size < (size_t)WS_NEED) return;  // clean fail (diagnosable), no OOB

  // workspace layout
  char* ws = (char*)d_ws;
  unsigned int* flags = (unsigned int*)(ws + 0);     // 16 KB (256 x 64B lines)
  unsigned int* go = (unsigned int*)(ws + 16384);    // 16 KB (1 line used)
  float* yring = (float*)(ws + 32768);               // 64 KB (4 slots x [4][1024])
  float* h1ring = (float*)(ws + 98304);              // 64 KB
  float* gx0 = (float*)(ws + 163840);                // 48 KB
  float* h2 = (float*)(ws + 212992);                 // 16 MB  [4][1024][1024]

  // flags/go/rings must be zero every call (ws is re-poisoned by harness)
  (void)hipMemsetAsync(d_ws, 0, 163840, stream);

  k_gx0<<<dim3(3072), dim3(256), 0, stream>>>(emb, w_ih0, b_ih0, gx0);

  void* args[] = {(void*)&w_hh0, (void*)&b_hh0, (void*)&w_ih1, (void*)&w_hh1,
                  (void*)&b_ih1, (void*)&b_hh1, (void*)&gx0,   (void*)&yring,
                  (void*)&h1ring, (void*)&h2,   (void*)&flags, (void*)&go};
  hipError_t ce = hipLaunchCooperativeKernel((void*)k_recur, dim3(NWG), dim3(512),
                                             args, 0, stream);
  if (ce != hipSuccess) {
    // fallback: plain launch; 256 WGs on 256 CUs co-reside, barrier still works
    k_recur<<<dim3(NWG), dim3(512), 0, stream>>>(w_hh0, b_hh0, w_ih1, w_hh1,
                                                 b_ih1, b_hh1, gx0, yring,
                                                 h1ring, h2, flags, go);
  }

  k_film_apply<<<dim3(16, 9, 4), dim3(256), 0, stream>>>(
      h2, w_scale, b_scale, w_shift, b_shift, x, out);
}

// Round 12
// 8311.105 us; speedup vs baseline: 3.7681x; 2.9915x over previous
//
#include <hip/hip_runtime.h>
#include <stdint.h>

// ---------------------------------------------------------------------------
// RNN-FiLM on MI355X.
// Shapes: B=4, C=2, E=512, H=1024, T=1024, F=513.
// Phases:
//   1. k_gx0: gx0 = emb @ w_ih0^T + b_ih0          (constant over time!)
//   2. k_recur: cooperative persistent kernel, both GRU layers pipelined with
//      one grid barrier per step (1025 steps). Weights in VGPRs, h-vectors
//      staged via LDS, DPP wave reductions.
//      R7: ALL cross-WG traffic via relaxed agent-scope atomics (sc1 -> LLC-
//      coherent, bypasses per-XCD L2). Zero buffer_wbl2 / buffer_inv per step
//      (R6 counters: 8% VALUBusy, ~22us/step lost to cache-maintenance from
//      release/acquire ops). Hand-rolled release = s_waitcnt vmcnt(0) + flag
//      store; all-to-all flag polling (no master relay).
//   3. k_film_apply: FiLM GEMM fused with the elementwise apply —
//      scale/shift tile lives in registers, never hits HBM.
// Workspace: [flags 16K | spare 16K | yring 64K | h1ring 64K | gx0 48K | h2 16M]
// ---------------------------------------------------------------------------

#define HH 1024
#define BB 4
#define TT 1024
#define EE 512
#define FF 513
#define NWG 256
#define NL0 85            // CUs owning layer-0 units
#define NL1 171           // CUs owning layer-1 units (NL0+NL1 == NWG)
#define NSTEP (TT + 1)    // pipeline depth 1 extra step
#define RMAX 5            // max weight rows per wave
#define WS_NEED 16990208  // bytes of d_ws we require

typedef unsigned long long ull_t;

__device__ __forceinline__ float sigmoidf_(float x) { return 1.0f / (1.0f + expf(-x)); }

// Relaxed agent-scope atomics: serviced at the coherence point (LLC), no
// cache-maintenance instructions, coherent across XCDs.
__device__ __forceinline__ void st_u32(unsigned int* p, unsigned int v) {
  __hip_atomic_store(p, v, __ATOMIC_RELAXED, __HIP_MEMORY_SCOPE_AGENT);
}
__device__ __forceinline__ unsigned int ld_u32(const unsigned int* p) {
  return __hip_atomic_load(p, __ATOMIC_RELAXED, __HIP_MEMORY_SCOPE_AGENT);
}
__device__ __forceinline__ void st_f32(float* p, float v) {
  __hip_atomic_store((unsigned int*)p, __float_as_uint(v),
                     __ATOMIC_RELAXED, __HIP_MEMORY_SCOPE_AGENT);
}
__device__ __forceinline__ ull_t ld_u64(const ull_t* p) {
  return __hip_atomic_load(p, __ATOMIC_RELAXED, __HIP_MEMORY_SCOPE_AGENT);
}

// Full wave64 sum via DPP (VALU pipe, keeps LDS pipe free). Result valid in lane 63.
__device__ __forceinline__ float wred_sum(float v) {
  int x = __float_as_int(v);
#define DPPADD(ctrl)                                                          \
  {                                                                           \
    int t_ = __builtin_amdgcn_update_dpp(0, x, (ctrl), 0xF, 0xF, true);       \
    x = __float_as_int(__int_as_float(x) + __int_as_float(t_));               \
  }
  DPPADD(0x111); // row_shr:1
  DPPADD(0x112); // row_shr:2
  DPPADD(0x114); // row_shr:4
  DPPADD(0x118); // row_shr:8   -> lane15 of each row16 holds row sum
  DPPADD(0x142); // row_bcast:15
  DPPADD(0x143); // row_bcast:31 -> lane 63 holds full sum
#undef DPPADD
  return __int_as_float(x);
}

// ------------------------- kernel 1: gx0 -----------------------------------
__global__ void k_gx0(const float* __restrict__ emb,
                      const float* __restrict__ w_ih0,
                      const float* __restrict__ b_ih0,
                      float* __restrict__ gx0) {
  int wave = threadIdx.x >> 6, lane = threadIdx.x & 63;
  int o = blockIdx.x * 4 + wave;  // 0..12287 = b*3072+g
  int b = o / 3072, g = o % 3072;
  const float* wr = w_ih0 + (size_t)g * EE + lane * 8;
  const float* er = emb + (size_t)b * EE + lane * 8;
  float4 w0 = *(const float4*)wr, w1 = *(const float4*)(wr + 4);
  float4 e0 = *(const float4*)er, e1 = *(const float4*)(er + 4);
  float s = w0.x * e0.x + w0.y * e0.y + w0.z * e0.z + w0.w * e0.w +
            w1.x * e1.x + w1.y * e1.y + w1.z * e1.z + w1.w * e1.w;
#pragma unroll
  for (int off = 32; off >= 1; off >>= 1) s += __shfl_xor(s, off);
  if (lane == 0) gx0[(size_t)b * 3072 + g] = s + b_ih0[g];
}

// ------------------------- kernel 2: recurrence ----------------------------
// Role 0 (wg < NL0): owns ~12 layer-0 units; step i computes y[i] from y[i-1].
// Role 1: owns ~6 layer-1 units; step i computes h1[i-1] from y[i-1], h1[i-2]
//   (gx1 and gh1 matvecs fused: waves 0-3 dot y, waves 4-7 dot h1).
// Rows per wave <= 5; lane k-slice: k = j*256 + lane*4 + c (j=0..3, c=0..3)
// -> all global/LDS accesses are consecutive-lane vector ops (conflict-free).
__launch_bounds__(512, 2)
__global__ void k_recur(const float* __restrict__ w_hh0,
                        const float* __restrict__ b_hh0,
                        const float* __restrict__ w_ih1,
                        const float* __restrict__ w_hh1,
                        const float* __restrict__ b_ih1,
                        const float* __restrict__ b_hh1,
                        const float* __restrict__ gx0,
                        float* __restrict__ yring,
                        float* __restrict__ h1ring,
                        float* __restrict__ h2,
                        unsigned int* __restrict__ flags) {
  const int tid = threadIdx.x;
  const int wave = tid >> 6, lane = tid & 63;
  const int wg = blockIdx.x;

  __shared__ float vlds[2][BB][HH];  // [0]=y_prev, [1]=h1_prev (role1 only)
  __shared__ float sums[40][BB];     // role0: rows 0..38 ; role1: gx m, gh 20+m

  int role, u0, nu;
  if (wg < NL0) {
    role = 0;
    const int q = HH / NL0, r = HH % NL0;  // 12, 4
    u0 = wg * q + (wg < r ? wg : r);
    nu = q + (wg < r ? 1 : 0);
  } else {
    role = 1;
    const int k = wg - NL0;
    const int q = HH / NL1, r = HH % NL1;  // 5, 169
    u0 = k * q + (k < r ? k : r);
    nu = q + (k < r ? 1 : 0);
  }
  const int L = 3 * nu;  // rows in this wave's list type
  int lbase, lstride, type;
  if (role == 0) { lbase = wave; lstride = 8; type = 0; }
  else           { lbase = wave & 3; lstride = 4; type = wave >> 2; }
  const float* Wmat = (role == 0) ? w_hh0 : (type == 0 ? w_ih1 : w_hh1);

  // -------- one-time weight preload into VGPRs (static indices only) -------
  float wreg[RMAX][16];
  int nr = 0;
#pragma unroll
  for (int jr = 0; jr < RMAX; ++jr) {
    int m = lbase + lstride * jr;
    if (m < L) {
      int u = m / 3, g = m % 3;
      const float* wp = Wmat + (size_t)(g * HH + u0 + u) * HH;
#pragma unroll
      for (int j = 0; j < 4; ++j) {
        float4 v = *(const float4*)(wp + j * 256 + lane * 4);
        wreg[jr][j * 4 + 0] = v.x; wreg[jr][j * 4 + 1] = v.y;
        wreg[jr][j * 4 + 2] = v.z; wreg[jr][j * 4 + 3] = v.w;
      }
      nr = jr + 1;
    }
  }

  // -------- gate-thread constants (gate threads all live in wave 0) --------
  const int gu = tid >> 2, gb = tid & 3;
  const bool gate = (tid < nu * 4);
  const int gj = u0 + gu;
  float c0 = 0.f, c1 = 0.f, c2 = 0.f, c3 = 0.f, c4 = 0.f, c5 = 0.f;
  if (gate) {
    if (role == 0) {  // gx0 (already includes b_ih0) + b_hh0
      c0 = gx0[(size_t)gb * 3072 + gj];
      c1 = gx0[(size_t)gb * 3072 + HH + gj];
      c2 = gx0[(size_t)gb * 3072 + 2 * HH + gj];
      c3 = b_hh0[gj]; c4 = b_hh0[HH + gj]; c5 = b_hh0[2 * HH + gj];
    } else {
      c0 = b_ih1[gj]; c1 = b_ih1[HH + gj]; c2 = b_ih1[2 * HH + gj];
      c3 = b_hh1[gj]; c4 = b_hh1[HH + gj]; c5 = b_hh1[2 * HH + gj];
    }
  }

  for (int i = 0; i < NSTEP; ++i) {
    const bool active = (role == 0) ? (i < TT) : (i >= 1);
    if (active) {
      // ---- stage vectors global(LLC) -> LDS via coherent u64 loads ----
      // 4096 floats = 2048 u64; 512 threads x 4 each, lane-consecutive.
      {
        const ull_t* src = (const ull_t*)(yring + (size_t)((i + 3) & 3) * BB * HH);
        ull_t* dst = (ull_t*)&vlds[0][0][0];
#pragma unroll
        for (int j = 0; j < 4; ++j) dst[j * 512 + tid] = ld_u64(src + j * 512 + tid);
      }
      if (role == 1) {
        const ull_t* src = (const ull_t*)(h1ring + (size_t)((i + 2) & 3) * BB * HH);
        ull_t* dst = (ull_t*)&vlds[1][0][0];
#pragma unroll
        for (int j = 0; j < 4; ++j) dst[j * 512 + tid] = ld_u64(src + j * 512 + tid);
      }
      __syncthreads();

      // ---- load this lane's h fragments (16 x ds_read_b128) ----
      float vreg[BB][16];
      const float* vb = &vlds[type][0][0];
#pragma unroll
      for (int b = 0; b < BB; ++b)
#pragma unroll
        for (int j = 0; j < 4; ++j) {
          float4 v = *(const float4*)(vb + b * HH + j * 256 + lane * 4);
          vreg[b][j * 4 + 0] = v.x; vreg[b][j * 4 + 1] = v.y;
          vreg[b][j * 4 + 2] = v.z; vreg[b][j * 4 + 3] = v.w;
        }

      // ---- matvec partials ----
      float acc[RMAX][BB];
#pragma unroll
      for (int jr = 0; jr < RMAX; ++jr)
#pragma unroll
        for (int b = 0; b < BB; ++b) acc[jr][b] = 0.f;
#pragma unroll
      for (int jr = 0; jr < RMAX; ++jr)
        if (jr < nr)
#pragma unroll
          for (int kk = 0; kk < 16; ++kk)
#pragma unroll
            for (int b = 0; b < BB; ++b)
              acc[jr][b] = fmaf(wreg[jr][kk], vreg[b][kk], acc[jr][b]);

      // ---- wave reductions (DPP, result in lane 63) ----
#pragma unroll
      for (int jr = 0; jr < RMAX; ++jr)
        if (jr < nr) {
          int m = lbase + lstride * jr;
#pragma unroll
          for (int b = 0; b < BB; ++b) {
            float s = wred_sum(acc[jr][b]);
            if (lane == 63) sums[(type ? 20 : 0) + m][b] = s;
          }
        }
      __syncthreads();

      // ---- gate math (<=52 threads, all in wave 0) ----
      if (gate) {
        if (role == 0) {
          float ghr = sums[3 * gu + 0][gb] + c3;
          float ghz = sums[3 * gu + 1][gb] + c4;
          float ghn = sums[3 * gu + 2][gb] + c5;
          float r_ = sigmoidf_(c0 + ghr);
          float z_ = sigmoidf_(c1 + ghz);
          float n_ = tanhf(c2 + r_ * ghn);
          float hp = vlds[0][gb][gj];
          float hn = (1.f - z_) * n_ + z_ * hp;
          st_f32(&yring[(size_t)(i & 3) * BB * HH + (size_t)gb * HH + gj], hn);
        } else {
          float gxr = sums[3 * gu + 0][gb] + c0;
          float gxz = sums[3 * gu + 1][gb] + c1;
          float gxn = sums[3 * gu + 2][gb] + c2;
          float ghr = sums[20 + 3 * gu + 0][gb] + c3;
          float ghz = sums[20 + 3 * gu + 1][gb] + c4;
          float ghn = sums[20 + 3 * gu + 2][gb] + c5;
          float r_ = sigmoidf_(gxr + ghr);
          float z_ = sigmoidf_(gxz + ghz);
          float n_ = tanhf(gxn + r_ * ghn);
          float hp = vlds[1][gb][gj];
          float hn = (1.f - z_) * n_ + z_ * hp;
          int t = i - 1;
          st_f32(&h1ring[(size_t)((i + 3) & 3) * BB * HH + (size_t)gb * HH + gj], hn);
          h2[((size_t)gb * TT + t) * HH + gj] = hn;  // plain: next-kernel only
        }
      }
    }

    // ---- grid barrier: all-to-all flags, relaxed atomics only ----
    // Data stores (sc1, LLC) were issued by wave 0; s_waitcnt vmcnt(0) in
    // wave 0 = hand-rolled release (no buffer_wbl2: nothing dirty in L2).
    // Consumer reads are sc1 loads -> no acquire invalidate needed.
    __syncthreads();
    const unsigned int want = (unsigned int)(i + 1);
    if (wave == 0) {
      asm volatile("s_waitcnt vmcnt(0)" ::: "memory");
      if (lane == 0) st_u32(&flags[wg * 16], want);
      int tries = 0;
      for (;;) {
        unsigned int f0 = ld_u32(&flags[(lane + 0) * 16]);
        unsigned int f1 = ld_u32(&flags[(lane + 64) * 16]);
        unsigned int f2 = ld_u32(&flags[(lane + 128) * 16]);
        unsigned int f3 = ld_u32(&flags[(lane + 192) * 16]);
        bool ok = (f0 >= want) && (f1 >= want) && (f2 >= want) && (f3 >= want);
        if (__all(ok) || ++tries >= 16384) break;
        __builtin_amdgcn_s_sleep(1);
      }
    }
    __syncthreads();
    asm volatile("" ::: "memory");  // compiler-only fence (no cache ops)
  }
}

// ------------------- kernel 3: FiLM GEMM + apply (fused) -------------------
// Per block: compute the 64(t) x 64(f) scale/shift tile for batch b1 in
// registers, then apply to all 8 (b2,c) x-tiles:
//   out[b1][b2][c][f][t] = x[b2][c][f][t] * S[b1][f][t] + Sh[b1][f][t]
__global__ void k_film_apply(const float* __restrict__ h2,
                             const float* __restrict__ w_scale,
                             const float* __restrict__ b_scale,
                             const float* __restrict__ w_shift,
                             const float* __restrict__ b_shift,
                             const float* __restrict__ x,
                             float* __restrict__ out) {
  __shared__ float As[64][36];
  __shared__ float Ws[2][64][36];
  const int tid = threadIdx.x;
  const int t0 = blockIdx.x * 64, f0 = blockIdx.y * 64, b1 = blockIdx.z;
  const int tx = tid & 15, ty = tid >> 4;
  float accS[4][4], accH[4][4];  // [i over t][j over f]
#pragma unroll
  for (int i = 0; i < 4; ++i)
#pragma unroll
    for (int j = 0; j < 4; ++j) { accS[i][j] = 0.f; accH[i][j] = 0.f; }

  const int lrow = tid >> 2, lj = tid & 3;
  for (int k0 = 0; k0 < HH; k0 += 32) {
    {
      const float* src = h2 + ((size_t)b1 * TT + (t0 + lrow)) * HH + k0;
      *(float4*)&As[lrow][lj * 4] = *(const float4*)(src + lj * 4);
      *(float4*)&As[lrow][(lj + 4) * 4] = *(const float4*)(src + (lj + 4) * 4);
    }
    {
      int f = f0 + lrow;
      float4 z4 = make_float4(0.f, 0.f, 0.f, 0.f);
      bool ok = (f < FF);
      const float* ss = w_scale + (size_t)f * HH + k0;
      const float* sh = w_shift + (size_t)f * HH + k0;
      *(float4*)&Ws[0][lrow][lj * 4] = ok ? *(const float4*)(ss + lj * 4) : z4;
      *(float4*)&Ws[0][lrow][(lj + 4) * 4] = ok ? *(const float4*)(ss + (lj + 4) * 4) : z4;
      *(float4*)&Ws[1][lrow][lj * 4] = ok ? *(const float4*)(sh + lj * 4) : z4;
      *(float4*)&Ws[1][lrow][(lj + 4) * 4] = ok ? *(const float4*)(sh + (lj + 4) * 4) : z4;
    }
    __syncthreads();
#pragma unroll
    for (int kk = 0; kk < 32; kk += 4) {
      float4 a4[4], s4[4], h4[4];
#pragma unroll
      for (int i = 0; i < 4; ++i) a4[i] = *(const float4*)&As[tx * 4 + i][kk];
#pragma unroll
      for (int j = 0; j < 4; ++j) {
        s4[j] = *(const float4*)&Ws[0][ty * 4 + j][kk];
        h4[j] = *(const float4*)&Ws[1][ty * 4 + j][kk];
      }
#pragma unroll
      for (int i = 0; i < 4; ++i)
#pragma unroll
        for (int j = 0; j < 4; ++j) {
          accS[i][j] = fmaf(a4[i].x, s4[j].x, accS[i][j]);
          accS[i][j] = fmaf(a4[i].y, s4[j].y, accS[i][j]);
          accS[i][j] = fmaf(a4[i].z, s4[j].z, accS[i][j]);
          accS[i][j] = fmaf(a4[i].w, s4[j].w, accS[i][j]);
          accH[i][j] = fmaf(a4[i].x, h4[j].x, accH[i][j]);
          accH[i][j] = fmaf(a4[i].y, h4[j].y, accH[i][j]);
          accH[i][j] = fmaf(a4[i].z, h4[j].z, accH[i][j]);
          accH[i][j] = fmaf(a4[i].w, h4[j].w, accH[i][j]);
        }
    }
    __syncthreads();
  }

  // ---- apply phase: this thread owns t = t0+tx*4..+3, f = f0+ty*4+j ----
#pragma unroll
  for (int j = 0; j < 4; ++j) {
    const int f = f0 + ty * 4 + j;
    if (f < FF) {
      const float bs = b_scale[f], bh = b_shift[f];
      const float s0 = accS[0][j] + bs, s1 = accS[1][j] + bs,
                  s2 = accS[2][j] + bs, s3 = accS[3][j] + bs;
      const float h0 = accH[0][j] + bh, h1 = accH[1][j] + bh,
                  h2v = accH[2][j] + bh, h3 = accH[3][j] + bh;
#pragma unroll
      for (int bc = 0; bc < 8; ++bc) {
        const int b2 = bc >> 1, c = bc & 1;
        const float4 xv = *(const float4*)(
            x + ((size_t)(b2 * 2 + c) * FF + f) * TT + t0 + tx * 4);
        float4 o;
        o.x = fmaf(xv.x, s0, h0);
        o.y = fmaf(xv.y, s1, h1);
        o.z = fmaf(xv.z, s2, h2v);
        o.w = fmaf(xv.w, s3, h3);
        *(float4*)(out + ((((size_t)b1 * 4 + b2) * 2 + c) * FF + f) * TT +
                   t0 + tx * 4) = o;
      }
    }
  }
}

// ------------------------- host launch -------------------------------------
extern "C" void kernel_launch(void* const* d_in, const int* in_sizes, int n_in,
                              void* d_out, int out_size, void* d_ws, size_t ws_size,
                              hipStream_t stream) {
  const float* x = (const float*)d_in[0];
  const float* emb = (const float*)d_in[1];
  const float* w_ih0 = (const float*)d_in[2];
  const float* w_hh0 = (const float*)d_in[3];
  const float* b_ih0 = (const float*)d_in[4];
  const float* b_hh0 = (const float*)d_in[5];
  const float* w_ih1 = (const float*)d_in[6];
  const float* w_hh1 = (const float*)d_in[7];
  const float* b_ih1 = (const float*)d_in[8];
  const float* b_hh1 = (const float*)d_in[9];
  const float* w_scale = (const float*)d_in[10];
  const float* b_scale = (const float*)d_in[11];
  const float* w_shift = (const float*)d_in[12];
  const float* b_shift = (const float*)d_in[13];
  float* out = (float*)d_out;

  if (ws_size < (size_t)WS_NEED) return;  // clean fail (diagnosable), no OOB

  // workspace layout
  char* ws = (char*)d_ws;
  unsigned int* flags = (unsigned int*)(ws + 0);     // 16 KB (256 x 64B lines)
  float* yring = (float*)(ws + 32768);               // 64 KB (4 slots x [4][1024])
  float* h1ring = (float*)(ws + 98304);              // 64 KB
  float* gx0 = (float*)(ws + 163840);                // 48 KB
  float* h2 = (float*)(ws + 212992);                 // 16 MB  [4][1024][1024]

  // flags/rings must be zero every call (ws is re-poisoned by harness)
  (void)hipMemsetAsync(d_ws, 0, 163840, stream);

  k_gx0<<<dim3(3072), dim3(256), 0, stream>>>(emb, w_ih0, b_ih0, gx0);

  void* args[] = {(void*)&w_hh0, (void*)&b_hh0, (void*)&w_ih1, (void*)&w_hh1,
                  (void*)&b_ih1, (void*)&b_hh1, (void*)&gx0,   (void*)&yring,
                  (void*)&h1ring, (void*)&h2,   (void*)&flags};
  hipError_t ce = hipLaunchCooperativeKernel((void*)k_recur, dim3(NWG), dim3(512),
                                             args, 0, stream);
  if (ce != hipSuccess) {
    // fallback: plain launch; 256 WGs on 256 CUs co-reside, barrier still works
    k_recur<<<dim3(NWG), dim3(512), 0, stream>>>(w_hh0, b_hh0, w_ih1, w_hh1,
                                                 b_ih1, b_hh1, gx0, yring,
                                                 h1ring, h2, flags);
  }

  k_film_apply<<<dim3(16, 9, 4), dim3(256), 0, stream>>>(
      h2, w_scale, b_scale, w_shift, b_shift, x, out);
}